// Round 6
// baseline (27.373 us; speedup 1.0000x reference)
//
#include <hip/hip_runtime.h>

#define EMBED 512
#define NTOK 8192
#define MT 16            // tokens per tile (one MFMA M-tile)
#define NB1 6            // GEMM1 N-fragments (96 cols = 16 h | 64 G | 4 xb | pad)
#define KS1 16           // GEMM1 K-steps (512/32)
#define NB2 32           // GEMM2 N-fragments (512 cols)
#define KS2 3            // GEMM2 K-steps (96/32; rows 68..95 zero)
#define B1ELEMS (KS1 * NB1 * 64 * 8)   // 49152
#define B2ELEMS (KS2 * NB2 * 64 * 8)   // 49152
#define XR 520           // LDS x row pitch (halves): 1040 B == 4 banks mod 32
#define ZR 104           // LDS z row pitch (halves): 208 B == 20 banks mod 32

using half8   = __attribute__((ext_vector_type(8))) _Float16;
using half2_t = __attribute__((ext_vector_type(2))) _Float16;
using f32x4   = __attribute__((ext_vector_type(4))) float;

#define MFMA16(a, b, c) __builtin_amdgcn_mfma_f32_16x16x32_f16((a), (b), (c), 0, 0, 0)

__device__ __forceinline__ half2_t pkrtz(float a, float b) {
    return __builtin_bit_cast(half2_t, __builtin_amdgcn_cvt_pkrtz(a, b));
}

// ---------------------------------------------------------------------------
// prep: pack B1 [512 x 96] and B2 [96 x 512] (f16, RNE) in MFMA B-frag order:
// frag(kstep, nf): lane l supplies B[k = kstep*32 + (l>>4)*8 + i][col = nf*16 + (l&15)]
// flat [kstep][nf][lane][i] -> coalesced 16B/lane in main.
// ---------------------------------------------------------------------------
__global__ __launch_bounds__(256) void prep(const float* __restrict__ fc1w,
                                            const float* __restrict__ fc2w,
                                            const float* __restrict__ fc2b,
                                            _Float16* __restrict__ b1f,
                                            _Float16* __restrict__ b2f)
{
    const int i = blockIdx.x * 256 + threadIdx.x;      // 0..49151
    // ---- B1: cols 0-15 fc1w^T | 16-79 W1[e][j][k] | 80-83 b1[e][j] | 84+ zero
    {
        const int elem = i & 7, lane = (i >> 3) & 63, rest = i >> 9;
        const int nf = rest % NB1, kstep = rest / NB1;
        const int krow = kstep * 32 + (lane >> 4) * 8 + elem;         // e
        const int c = nf * 16 + (lane & 15);
        float v;
        if (c < 16)      v = fc1w[c * EMBED + krow];
        else if (c < 80) { int cc = c - 16; v = fc2w[(krow * 4 + (cc >> 4)) * 16 + (cc & 15)]; }
        else if (c < 84) v = fc2b[krow * 4 + (c - 80)];
        else             v = 0.f;
        b1f[i] = (_Float16)v;
    }
    // ---- B2: rows j*16+k -> W2[j][e][k]; rows 64+j -> b2[j][e]; rows 68+ zero
    {
        const int elem = i & 7, lane = (i >> 3) & 63, rest = i >> 9;
        const int nf = rest & 31, kstep = rest >> 5;
        const int krow = kstep * 32 + (lane >> 4) * 8 + elem;         // 0..95
        const int e = nf * 16 + (lane & 15);
        float v;
        if (krow < 64)      v = fc2w[(2048 + (krow >> 4) * 512 + e) * 16 + (krow & 15)];
        else if (krow < 68) v = fc2b[2048 + (krow - 64) * 512 + e];
        else                v = 0.f;
        b2f[i] = (_Float16)v;
    }
}

// ---------------------------------------------------------------------------
// main: block b -> tile (b>>1), N-half (b&1). GEMM1+glue duplicated per half;
// GEMM2 split 16 frags/block. 1024 blocks -> 4 blocks/CU (16 waves/CU).
// ---------------------------------------------------------------------------
__global__ __launch_bounds__(256, 4) void hyper_main(const float* __restrict__ x,
                                                     const float* __restrict__ fc1b,
                                                     const _Float16* __restrict__ b1f,
                                                     const _Float16* __restrict__ b2f,
                                                     float* __restrict__ out)
{
    __shared__ _Float16 xh[MT][XR];         // 16.6 KB f16 x-tile
    __shared__ float    c1s[MT][100];       // 6.4 KB GEMM1 result spill
    __shared__ _Float16 zh[MT][ZR];         // 3.3 KB Z (f16)

    const int tid  = threadIdx.x;
    const int lane = tid & 63;
    const int wv   = tid >> 6;
    const int rowA = lane & 15;             // token row inside tile
    const int kgrp = lane >> 4;             // 0..3
    const int nh   = blockIdx.x & 1;        // N-half of GEMM2
    const long tok0 = (long)(blockIdx.x >> 1) * MT;

    // ---- stage x: 16 x 512 f32 -> f16 LDS (coalesced, converted once) ------
    {
        const float4* xg = reinterpret_cast<const float4*>(x + tok0 * EMBED);
        #pragma unroll
        for (int i = 0; i < 8; ++i) {
            const int idx = tid + i * 256;            // 2048 float4
            float4 v = xg[idx];
            const int t = idx >> 7, e4 = idx & 127;
            half2_t p0 = pkrtz(v.x, v.y), p1 = pkrtz(v.z, v.w);
            uint2 w;
            w.x = __builtin_bit_cast(unsigned, p0);
            w.y = __builtin_bit_cast(unsigned, p1);
            *reinterpret_cast<uint2*>(&xh[t][e4 * 4]) = w;
        }
    }
    __syncthreads();

    // ================= GEMM1: X[16x512] * B1[512x96] =========================
    f32x4 accA = {0.f, 0.f, 0.f, 0.f};
    f32x4 accB = {0.f, 0.f, 0.f, 0.f};
    const int nfA = wv;
    const int nfB = 4 + wv;
    const bool hasB = (wv < 2);

    #pragma unroll
    for (int ks = 0; ks < KS1; ++ks) {
        half8 a = *reinterpret_cast<const half8*>(&xh[rowA][ks * 32 + kgrp * 8]);
        half8 bA = *reinterpret_cast<const half8*>(b1f + ((ks * NB1 + nfA) * 64 + lane) * 8);
        accA = MFMA16(a, bA, accA);
        if (hasB) {
            half8 bB = *reinterpret_cast<const half8*>(b1f + ((ks * NB1 + nfB) * 64 + lane) * 8);
            accB = MFMA16(a, bB, accB);
        }
    }
    #pragma unroll
    for (int r = 0; r < 4; ++r) c1s[kgrp * 4 + r][nfA * 16 + rowA] = accA[r];
    if (hasB) {
        #pragma unroll
        for (int r = 0; r < 4; ++r) c1s[kgrp * 4 + r][nfB * 16 + rowA] = accB[r];
    }
    __syncthreads();

    // ================= glue: h, y1, Z = (y1 (x) h | y1 | 0) ==================
    if (tid < 64) {
        const int t = tid & 15, j = tid >> 4;
        float h[16];
        #pragma unroll
        for (int k = 0; k < 16; ++k) h[k] = fmaxf(c1s[t][k] + fc1b[k], 0.f);
        float y1 = c1s[t][80 + j];
        #pragma unroll
        for (int k = 0; k < 16; ++k) y1 = fmaf(c1s[t][16 + j * 16 + k], h[k], y1);
        y1 = fmaxf(y1, 0.f);
        #pragma unroll
        for (int k = 0; k < 16; k += 2) {
            half2_t p = pkrtz(y1 * h[k], y1 * h[k + 1]);
            *reinterpret_cast<half2_t*>(&zh[t][j * 16 + k]) = p;
        }
        zh[t][64 + j] = (_Float16)y1;
        #pragma unroll
        for (int p = 0; p < 7; ++p) zh[t][68 + j * 7 + p] = (_Float16)0.f;
    }
    __syncthreads();

    // ================= GEMM2 (this block's half): Z[16x96] * B2[96x256] ======
    f32x4 acc2[4];
    #pragma unroll
    for (int f = 0; f < 4; ++f) acc2[f] = (f32x4){0.f, 0.f, 0.f, 0.f};

    #pragma unroll
    for (int ks = 0; ks < KS2; ++ks) {
        half8 az = *reinterpret_cast<const half8*>(&zh[rowA][ks * 32 + kgrp * 8]);
        #pragma unroll
        for (int f = 0; f < 4; ++f) {
            const int nf2 = nh * 16 + wv * 4 + f;
            half8 bv = *reinterpret_cast<const half8*>(b2f + ((ks * NB2 + nf2) * 64 + lane) * 8);
            acc2[f] = MFMA16(az, bv, acc2[f]);
        }
    }

    // ================= relu + store ==========================================
    #pragma unroll
    for (int f = 0; f < 4; ++f) {
        const int e = (nh * 16 + wv * 4 + f) * 16 + rowA;
        #pragma unroll
        for (int r = 0; r < 4; ++r) {
            out[(tok0 + kgrp * 4 + r) * EMBED + e] = fmaxf(acc2[f][r], 0.f);
        }
    }
}

extern "C" void kernel_launch(void* const* d_in, const int* in_sizes, int n_in,
                              void* d_out, int out_size, void* d_ws, size_t ws_size,
                              hipStream_t stream) {
    const float* x    = (const float*)d_in[0];
    const float* fc1w = (const float*)d_in[1];
    const float* fc1b = (const float*)d_in[2];
    const float* fc2w = (const float*)d_in[3];
    const float* fc2b = (const float*)d_in[4];
    float* out = (float*)d_out;

    _Float16* b1f = (_Float16*)d_ws;                   // 96 KB
    _Float16* b2f = b1f + B1ELEMS;                     // 96 KB

    prep<<<dim3(B1ELEMS / 256), dim3(256), 0, stream>>>(fc1w, fc2w, fc2b, b1f, b2f);
    hyper_main<<<dim3(2 * NTOK / MT), dim3(256), 0, stream>>>(x, fc1b, b1f, b2f, out);
}